// Round 1
// baseline (3466.034 us; speedup 1.0000x reference)
//
#include <hip/hip_runtime.h>
#include <float.h>

#define N_NODES 50000
#define N_EDGES 600000
#define D 128
#define N_GRAPHS 64
#define BM 64
#define BK 32
#define SEG_CHUNK 512

__global__ void zero_f4(float4* __restrict__ p, int n4) {
    int i = blockIdx.x * 256 + threadIdx.x;
    if (i < n4) p[i] = make_float4(0.f, 0.f, 0.f, 0.f);
}

__global__ void init_neg(float* __restrict__ p, int n) {
    int i = blockIdx.x * 256 + threadIdx.x;
    if (i < n) p[i] = -FLT_MAX;
}

// agg[dst] += x[src], one thread per (edge, 4-feature group)
__global__ void scatter_add(const float* __restrict__ x, const int* __restrict__ ei,
                            float* __restrict__ agg) {
    int idx = blockIdx.x * 256 + threadIdx.x;
    if (idx >= N_EDGES * 32) return;
    int e  = idx >> 5;
    int d4 = idx & 31;
    int src = ei[e];
    int dst = ei[N_EDGES + e];
    const float4 v = *(const float4*)(x + (size_t)src * D + d4 * 4);
    float* o = agg + (size_t)dst * D + d4 * 4;
    atomicAdd(o + 0, v.x);
    atomicAdd(o + 1, v.y);
    atomicAdd(o + 2, v.z);
    atomicAdd(o + 3, v.w);
}

// WT[k][o] for k<128: W_rel[o][k]; k>=128: W_root[o][k-128]
__global__ void transpose_w(const float* __restrict__ Wrel, const float* __restrict__ Wroot,
                            float* __restrict__ WT) {
    int idx = blockIdx.x * 256 + threadIdx.x;
    if (idx >= 256 * 128) return;
    int k = idx >> 7, o = idx & 127;
    WT[idx] = (k < 128) ? Wrel[o * 128 + k] : Wroot[o * 128 + (k - 128)];
}

// O[M,128] = A[M,128] @ WT[0:128] + X[M,128] @ WT[128:256] + bias, optional relu
// (single K=256 GEMM over concatenated [A|X])
__global__ __launch_bounds__(256) void gemm_fused(
    const float* __restrict__ A, const float* __restrict__ X,
    const float* __restrict__ WT, const float* __restrict__ bias,
    float* __restrict__ O, int relu)
{
    __shared__ float As[BM][BK + 4];   // +4 pad keeps 16B alignment, breaks stride-32 banks
    __shared__ float Bs[BK][D];
    int tid = threadIdx.x;
    int tx = tid & 31;      // col group: cols tx*4 .. tx*4+3
    int ty = tid >> 5;      // row group: rows ty*8 .. ty*8+7
    int row0 = blockIdx.x * BM;

    float acc[8][4];
#pragma unroll
    for (int r = 0; r < 8; ++r)
#pragma unroll
        for (int c = 0; c < 4; ++c) acc[r][c] = 0.f;

    for (int kt = 0; kt < 2 * D; kt += BK) {
        // B tile: 32x128 floats, 256 threads x 4 float4
#pragma unroll
        for (int i = 0; i < 4; ++i) {
            int f4 = tid + i * 256;        // 0..1023
            int k  = f4 >> 5;
            int c4 = f4 & 31;
            *(float4*)(&Bs[k][c4 * 4]) = *(const float4*)(WT + (size_t)(kt + k) * D + c4 * 4);
        }
        // A tile: 64 rows x 32 k, 256 threads x 2 float4; source switches at k=128
        const float* S = (kt < D) ? A : X;
        int kk = kt & (D - 1);
#pragma unroll
        for (int i = 0; i < 2; ++i) {
            int f4 = tid + i * 256;        // 0..511
            int r  = f4 >> 3;
            int c4 = f4 & 7;
            int grow = row0 + r;
            float4 v = make_float4(0.f, 0.f, 0.f, 0.f);
            if (grow < N_NODES) v = *(const float4*)(S + (size_t)grow * D + kk + c4 * 4);
            *(float4*)(&As[r][c4 * 4]) = v;
        }
        __syncthreads();
#pragma unroll
        for (int k = 0; k < BK; k += 2) {
            float4 b0 = *(const float4*)(&Bs[k][tx * 4]);
            float4 b1 = *(const float4*)(&Bs[k + 1][tx * 4]);
#pragma unroll
            for (int r = 0; r < 8; ++r) {
                float2 a = *(const float2*)(&As[ty * 8 + r][k]);
                acc[r][0] += a.x * b0.x; acc[r][1] += a.x * b0.y;
                acc[r][2] += a.x * b0.z; acc[r][3] += a.x * b0.w;
                acc[r][0] += a.y * b1.x; acc[r][1] += a.y * b1.y;
                acc[r][2] += a.y * b1.z; acc[r][3] += a.y * b1.w;
            }
        }
        __syncthreads();
    }

    float4 bv = *(const float4*)(bias + tx * 4);
#pragma unroll
    for (int r = 0; r < 8; ++r) {
        int grow = row0 + ty * 8 + r;
        if (grow >= N_NODES) continue;
        float4 v;
        v.x = acc[r][0] + bv.x; v.y = acc[r][1] + bv.y;
        v.z = acc[r][2] + bv.z; v.w = acc[r][3] + bv.w;
        if (relu) {
            v.x = fmaxf(v.x, 0.f); v.y = fmaxf(v.y, 0.f);
            v.z = fmaxf(v.z, 0.f); v.w = fmaxf(v.w, 0.f);
        }
        *(float4*)(O + (size_t)grow * D + tx * 4) = v;
    }
}

__device__ inline void atomicMaxF(float* addr, float v) {
    // int-max for non-negative, unsigned-min for negative; init must be -FLT_MAX
    if (v >= 0.f) atomicMax((int*)addr, __float_as_int(v));
    else          atomicMin((unsigned int*)addr, __float_as_uint(v));
}

// batch is sorted; each block runs SEG_CHUNK nodes, thread d tracks feature d,
// flushing with an atomic only at graph boundaries.
__global__ void seg_max(const float* __restrict__ h, const int* __restrict__ batch,
                        float* __restrict__ g) {
    int d  = threadIdx.x;              // 128
    int n0 = blockIdx.x * SEG_CHUNK;
    int nend = min(n0 + SEG_CHUNK, N_NODES);
    int cur_b = batch[n0];
    float cur = -FLT_MAX;
    for (int n = n0; n < nend; ++n) {
        int b = batch[n];
        if (b != cur_b) {
            atomicMaxF(&g[cur_b * D + d], cur);
            cur_b = b;
            cur = -FLT_MAX;
        }
        cur = fmaxf(cur, h[(size_t)n * D + d]);
    }
    atomicMaxF(&g[cur_b * D + d], cur);
}

__global__ void mlp_head(const float* __restrict__ g,
                         const float* __restrict__ W1, const float* __restrict__ b1,
                         const float* __restrict__ W2, const float* __restrict__ b2,
                         float* __restrict__ out) {
    int gi = threadIdx.x;
    if (gi >= N_GRAPHS) return;
    float h[5];
#pragma unroll
    for (int j = 0; j < 5; ++j) {
        float acc = b1[j];
        for (int k = 0; k < D; ++k) acc += g[gi * D + k] * W1[j * D + k];
        h[j] = fmaxf(acc, 0.f);
    }
    float o = b2[0];
#pragma unroll
    for (int j = 0; j < 5; ++j) o += h[j] * W2[j];
    out[gi] = o;
}

extern "C" void kernel_launch(void* const* d_in, const int* in_sizes, int n_in,
                              void* d_out, int out_size, void* d_ws, size_t ws_size,
                              hipStream_t stream) {
    const float* x     = (const float*)d_in[0];
    const int*   ei    = (const int*)d_in[1];     // [2, E] int32
    const int*   batch = (const int*)d_in[2];
    const float* Wrel[3]  = {(const float*)d_in[3], (const float*)d_in[6], (const float*)d_in[9]};
    const float* brel[3]  = {(const float*)d_in[4], (const float*)d_in[7], (const float*)d_in[10]};
    const float* Wroot[3] = {(const float*)d_in[5], (const float*)d_in[8], (const float*)d_in[11]};
    const float* W1 = (const float*)d_in[12];
    const float* b1 = (const float*)d_in[13];
    const float* W2 = (const float*)d_in[14];
    const float* b2 = (const float*)d_in[15];
    float* out = (float*)d_out;

    char* ws = (char*)d_ws;
    const size_t nodeBytes = (size_t)N_NODES * D * sizeof(float);   // 25.6 MB
    float* agg  = (float*)(ws);
    float* buf1 = (float*)(ws + nodeBytes);
    float* buf2 = (float*)(ws + 2 * nodeBytes);
    float* WT0  = (float*)(ws + 3 * nodeBytes);
    float* WT1  = WT0 + 256 * 128;
    float* WT2  = WT1 + 256 * 128;
    float* g    = WT2 + 256 * 128;                 // 64*128 floats
    float* WT[3] = {WT0, WT1, WT2};

    for (int l = 0; l < 3; ++l)
        transpose_w<<<128, 256, 0, stream>>>(Wrel[l], Wroot[l], WT[l]);

    const int n4 = N_NODES * D / 4;                // 1.6M float4
    const float* cur = x;
    float* outs[3] = {buf1, buf2, buf1};
    for (int l = 0; l < 3; ++l) {
        zero_f4<<<(n4 + 255) / 256, 256, 0, stream>>>((float4*)agg, n4);
        scatter_add<<<(N_EDGES * 32 + 255) / 256, 256, 0, stream>>>(cur, ei, agg);
        gemm_fused<<<(N_NODES + BM - 1) / BM, 256, 0, stream>>>(
            agg, cur, WT[l], brel[l], outs[l], (l < 2) ? 1 : 0);
        cur = outs[l];
    }

    init_neg<<<(N_GRAPHS * D + 255) / 256, 256, 0, stream>>>(g, N_GRAPHS * D);
    seg_max<<<(N_NODES + SEG_CHUNK - 1) / SEG_CHUNK, 128, 0, stream>>>(cur, batch, g);
    mlp_head<<<1, 64, 0, stream>>>(g, W1, b1, W2, b2, out);
}

// Round 2
// 715.635 us; speedup vs baseline: 4.8433x; 4.8433x over previous
//
#include <hip/hip_runtime.h>
#include <float.h>

#define N_NODES 50000
#define N_EDGES 600000
#define D 128
#define N_GRAPHS 64
#define BM 64
#define BK 32
#define SEG_CHUNK 512
#define SCAN_T 256

__global__ void zero_i(int* __restrict__ p, int n) {
    int i = blockIdx.x * 256 + threadIdx.x;
    if (i < n) p[i] = 0;
}

__global__ void init_neg(float* __restrict__ p, int n) {
    int i = blockIdx.x * 256 + threadIdx.x;
    if (i < n) p[i] = -FLT_MAX;
}

// ---------------- CSR build (once per launch; edge_index is layer-invariant) ----

__global__ void count_deg(const int* __restrict__ ei, int* __restrict__ deg) {
    int e = blockIdx.x * 256 + threadIdx.x;
    if (e < N_EDGES) atomicAdd(&deg[ei[N_EDGES + e]], 1);
}

// single-block two-phase exclusive scan of deg[0..N_NODES) -> row_start, cursor
__global__ __launch_bounds__(SCAN_T) void scan_deg(const int* __restrict__ deg,
                                                   int* __restrict__ row_start,
                                                   int* __restrict__ cursor) {
    __shared__ int partial[SCAN_T];
    int tid = threadIdx.x;
    const int chunk = (N_NODES + SCAN_T - 1) / SCAN_T;   // 196
    int beg = tid * chunk;
    int end = min(beg + chunk, N_NODES);
    int sum = 0;
    for (int i = beg; i < end; ++i) sum += deg[i];
    partial[tid] = sum;
    __syncthreads();
    // Hillis-Steele inclusive scan over 256 partials
    for (int off = 1; off < SCAN_T; off <<= 1) {
        int v = (tid >= off) ? partial[tid - off] : 0;
        __syncthreads();
        partial[tid] += v;
        __syncthreads();
    }
    int run = (tid == 0) ? 0 : partial[tid - 1];
    for (int i = beg; i < end; ++i) {
        row_start[i] = run;
        cursor[i]    = run;
        run += deg[i];
    }
    if (end == N_NODES) row_start[N_NODES] = run;   // = N_EDGES
}

__global__ void fill_csr(const int* __restrict__ ei, int* __restrict__ cursor,
                         int* __restrict__ csr_src) {
    int e = blockIdx.x * 256 + threadIdx.x;
    if (e < N_EDGES) {
        int dst = ei[N_EDGES + e];
        int pos = atomicAdd(&cursor[dst], 1);
        csr_src[pos] = ei[e];
    }
}

// ---------------- aggregation: gather-sum, 32 lanes per node, float4/lane ------

__global__ __launch_bounds__(256) void csr_gather(
    const float* __restrict__ x, const int* __restrict__ row_start,
    const int* __restrict__ csr_src, float* __restrict__ agg)
{
    int node = blockIdx.x * 8 + (threadIdx.x >> 5);
    int lane = threadIdx.x & 31;
    if (node >= N_NODES) return;
    int beg = row_start[node];
    int end = row_start[node + 1];
    float4 a0 = make_float4(0.f, 0.f, 0.f, 0.f);
    float4 a1 = make_float4(0.f, 0.f, 0.f, 0.f);
    int i = beg;
    for (; i + 1 < end; i += 2) {
        int s0 = csr_src[i];
        int s1 = csr_src[i + 1];
        float4 v0 = *(const float4*)(x + (size_t)s0 * D + lane * 4);
        float4 v1 = *(const float4*)(x + (size_t)s1 * D + lane * 4);
        a0.x += v0.x; a0.y += v0.y; a0.z += v0.z; a0.w += v0.w;
        a1.x += v1.x; a1.y += v1.y; a1.z += v1.z; a1.w += v1.w;
    }
    if (i < end) {
        int s0 = csr_src[i];
        float4 v0 = *(const float4*)(x + (size_t)s0 * D + lane * 4);
        a0.x += v0.x; a0.y += v0.y; a0.z += v0.z; a0.w += v0.w;
    }
    a0.x += a1.x; a0.y += a1.y; a0.z += a1.z; a0.w += a1.w;
    *(float4*)(agg + (size_t)node * D + lane * 4) = a0;
}

// ---------------- fused GEMM: O = [agg|x] @ WT + b (opt relu) ------------------

__global__ void transpose_w(const float* __restrict__ Wrel, const float* __restrict__ Wroot,
                            float* __restrict__ WT) {
    int idx = blockIdx.x * 256 + threadIdx.x;
    if (idx >= 256 * 128) return;
    int k = idx >> 7, o = idx & 127;
    WT[idx] = (k < 128) ? Wrel[o * 128 + k] : Wroot[o * 128 + (k - 128)];
}

__global__ __launch_bounds__(256) void gemm_fused(
    const float* __restrict__ A, const float* __restrict__ X,
    const float* __restrict__ WT, const float* __restrict__ bias,
    float* __restrict__ O, int relu)
{
    __shared__ float As[BM][BK + 4];
    __shared__ float Bs[BK][D];
    int tid = threadIdx.x;
    int tx = tid & 31;
    int ty = tid >> 5;
    int row0 = blockIdx.x * BM;

    float acc[8][4];
#pragma unroll
    for (int r = 0; r < 8; ++r)
#pragma unroll
        for (int c = 0; c < 4; ++c) acc[r][c] = 0.f;

    for (int kt = 0; kt < 2 * D; kt += BK) {
#pragma unroll
        for (int i = 0; i < 4; ++i) {
            int f4 = tid + i * 256;
            int k  = f4 >> 5;
            int c4 = f4 & 31;
            *(float4*)(&Bs[k][c4 * 4]) = *(const float4*)(WT + (size_t)(kt + k) * D + c4 * 4);
        }
        const float* S = (kt < D) ? A : X;
        int kk = kt & (D - 1);
#pragma unroll
        for (int i = 0; i < 2; ++i) {
            int f4 = tid + i * 256;
            int r  = f4 >> 3;
            int c4 = f4 & 7;
            int grow = row0 + r;
            float4 v = make_float4(0.f, 0.f, 0.f, 0.f);
            if (grow < N_NODES) v = *(const float4*)(S + (size_t)grow * D + kk + c4 * 4);
            *(float4*)(&As[r][c4 * 4]) = v;
        }
        __syncthreads();
#pragma unroll
        for (int k = 0; k < BK; k += 2) {
            float4 b0 = *(const float4*)(&Bs[k][tx * 4]);
            float4 b1 = *(const float4*)(&Bs[k + 1][tx * 4]);
#pragma unroll
            for (int r = 0; r < 8; ++r) {
                float2 a = *(const float2*)(&As[ty * 8 + r][k]);
                acc[r][0] += a.x * b0.x; acc[r][1] += a.x * b0.y;
                acc[r][2] += a.x * b0.z; acc[r][3] += a.x * b0.w;
                acc[r][0] += a.y * b1.x; acc[r][1] += a.y * b1.y;
                acc[r][2] += a.y * b1.z; acc[r][3] += a.y * b1.w;
            }
        }
        __syncthreads();
    }

    float4 bv = *(const float4*)(bias + tx * 4);
#pragma unroll
    for (int r = 0; r < 8; ++r) {
        int grow = row0 + ty * 8 + r;
        if (grow >= N_NODES) continue;
        float4 v;
        v.x = acc[r][0] + bv.x; v.y = acc[r][1] + bv.y;
        v.z = acc[r][2] + bv.z; v.w = acc[r][3] + bv.w;
        if (relu) {
            v.x = fmaxf(v.x, 0.f); v.y = fmaxf(v.y, 0.f);
            v.z = fmaxf(v.z, 0.f); v.w = fmaxf(v.w, 0.f);
        }
        *(float4*)(O + (size_t)grow * D + tx * 4) = v;
    }
}

// ---------------- pooling + head ----------------------------------------------

__device__ inline void atomicMaxF(float* addr, float v) {
    if (v >= 0.f) atomicMax((int*)addr, __float_as_int(v));
    else          atomicMin((unsigned int*)addr, __float_as_uint(v));
}

__global__ void seg_max(const float* __restrict__ h, const int* __restrict__ batch,
                        float* __restrict__ g) {
    int d  = threadIdx.x;
    int n0 = blockIdx.x * SEG_CHUNK;
    int nend = min(n0 + SEG_CHUNK, N_NODES);
    int cur_b = batch[n0];
    float cur = -FLT_MAX;
    for (int n = n0; n < nend; ++n) {
        int b = batch[n];
        if (b != cur_b) {
            atomicMaxF(&g[cur_b * D + d], cur);
            cur_b = b;
            cur = -FLT_MAX;
        }
        cur = fmaxf(cur, h[(size_t)n * D + d]);
    }
    atomicMaxF(&g[cur_b * D + d], cur);
}

__global__ void mlp_head(const float* __restrict__ g,
                         const float* __restrict__ W1, const float* __restrict__ b1,
                         const float* __restrict__ W2, const float* __restrict__ b2,
                         float* __restrict__ out) {
    int gi = threadIdx.x;
    if (gi >= N_GRAPHS) return;
    float h[5];
#pragma unroll
    for (int j = 0; j < 5; ++j) {
        float acc = b1[j];
        for (int k = 0; k < D; ++k) acc += g[gi * D + k] * W1[j * D + k];
        h[j] = fmaxf(acc, 0.f);
    }
    float o = b2[0];
#pragma unroll
    for (int j = 0; j < 5; ++j) o += h[j] * W2[j];
    out[gi] = o;
}

extern "C" void kernel_launch(void* const* d_in, const int* in_sizes, int n_in,
                              void* d_out, int out_size, void* d_ws, size_t ws_size,
                              hipStream_t stream) {
    const float* x     = (const float*)d_in[0];
    const int*   ei    = (const int*)d_in[1];
    const int*   batch = (const int*)d_in[2];
    const float* Wrel[3]  = {(const float*)d_in[3], (const float*)d_in[6], (const float*)d_in[9]};
    const float* brel[3]  = {(const float*)d_in[4], (const float*)d_in[7], (const float*)d_in[10]};
    const float* Wroot[3] = {(const float*)d_in[5], (const float*)d_in[8], (const float*)d_in[11]};
    const float* W1 = (const float*)d_in[12];
    const float* b1 = (const float*)d_in[13];
    const float* W2 = (const float*)d_in[14];
    const float* b2 = (const float*)d_in[15];
    float* out = (float*)d_out;

    char* ws = (char*)d_ws;
    const size_t nodeBytes = (size_t)N_NODES * D * sizeof(float);   // 25.6 MB
    float* agg  = (float*)(ws);
    float* buf1 = (float*)(ws + nodeBytes);
    float* buf2 = (float*)(ws + 2 * nodeBytes);
    char*  p    = ws + 3 * nodeBytes;
    float* WT0  = (float*)p;            p += 256 * 128 * sizeof(float);
    float* WT1  = (float*)p;            p += 256 * 128 * sizeof(float);
    float* WT2  = (float*)p;            p += 256 * 128 * sizeof(float);
    float* g    = (float*)p;            p += N_GRAPHS * D * sizeof(float);
    int*   deg       = (int*)p;         p += N_NODES * sizeof(int);
    int*   row_start = (int*)p;         p += (N_NODES + 1) * sizeof(int);
    int*   cursor    = (int*)p;         p += N_NODES * sizeof(int);
    int*   csr_src   = (int*)p;         p += N_EDGES * sizeof(int);
    float* WT[3] = {WT0, WT1, WT2};

    // CSR build (once)
    zero_i<<<(N_NODES + 255) / 256, 256, 0, stream>>>(deg, N_NODES);
    count_deg<<<(N_EDGES + 255) / 256, 256, 0, stream>>>(ei, deg);
    scan_deg<<<1, SCAN_T, 0, stream>>>(deg, row_start, cursor);
    fill_csr<<<(N_EDGES + 255) / 256, 256, 0, stream>>>(ei, cursor, csr_src);

    for (int l = 0; l < 3; ++l)
        transpose_w<<<128, 256, 0, stream>>>(Wrel[l], Wroot[l], WT[l]);

    const float* cur = x;
    float* outs[3] = {buf1, buf2, buf1};
    for (int l = 0; l < 3; ++l) {
        csr_gather<<<(N_NODES + 7) / 8, 256, 0, stream>>>(cur, row_start, csr_src, agg);
        gemm_fused<<<(N_NODES + BM - 1) / BM, 256, 0, stream>>>(
            agg, cur, WT[l], brel[l], outs[l], (l < 2) ? 1 : 0);
        cur = outs[l];
    }

    init_neg<<<(N_GRAPHS * D + 255) / 256, 256, 0, stream>>>(g, N_GRAPHS * D);
    seg_max<<<(N_NODES + SEG_CHUNK - 1) / SEG_CHUNK, 128, 0, stream>>>(cur, batch, g);
    mlp_head<<<1, 64, 0, stream>>>(g, W1, b1, W2, b2, out);
}

// Round 3
// 597.401 us; speedup vs baseline: 5.8019x; 1.1979x over previous
//
#include <hip/hip_runtime.h>
#include <float.h>

#define N_NODES 50000
#define N_EDGES 600000
#define D 128
#define N_GRAPHS 64
#define BM 64
#define BK 32
#define SEG_CHUNK 32
#define SCAN_T 256

__global__ void zero_i(int* __restrict__ p, int n) {
    int i = blockIdx.x * 256 + threadIdx.x;
    if (i < n) p[i] = 0;
}

__global__ void init_neg(float* __restrict__ p, int n) {
    int i = blockIdx.x * 256 + threadIdx.x;
    if (i < n) p[i] = -FLT_MAX;
}

// ---------------- CSR build (once per launch; edge_index is layer-invariant) ----

__global__ void count_deg(const int* __restrict__ ei, int* __restrict__ deg) {
    int e = blockIdx.x * 256 + threadIdx.x;
    if (e < N_EDGES) atomicAdd(&deg[ei[N_EDGES + e]], 1);
}

// single-block two-phase exclusive scan of deg[0..N_NODES) -> row_start, cursor
__global__ __launch_bounds__(SCAN_T) void scan_deg(const int* __restrict__ deg,
                                                   int* __restrict__ row_start,
                                                   int* __restrict__ cursor) {
    __shared__ int partial[SCAN_T];
    int tid = threadIdx.x;
    const int chunk = (N_NODES + SCAN_T - 1) / SCAN_T;   // 196
    int beg = tid * chunk;
    int end = min(beg + chunk, N_NODES);
    int sum = 0;
    for (int i = beg; i < end; ++i) sum += deg[i];
    partial[tid] = sum;
    __syncthreads();
    for (int off = 1; off < SCAN_T; off <<= 1) {
        int v = (tid >= off) ? partial[tid - off] : 0;
        __syncthreads();
        partial[tid] += v;
        __syncthreads();
    }
    int run = (tid == 0) ? 0 : partial[tid - 1];
    for (int i = beg; i < end; ++i) {
        row_start[i] = run;
        cursor[i]    = run;
        run += deg[i];
    }
    if (end == N_NODES) row_start[N_NODES] = run;   // = N_EDGES
}

__global__ void fill_csr(const int* __restrict__ ei, int* __restrict__ cursor,
                         int* __restrict__ csr_src) {
    int e = blockIdx.x * 256 + threadIdx.x;
    if (e < N_EDGES) {
        int dst = ei[N_EDGES + e];
        int pos = atomicAdd(&cursor[dst], 1);
        csr_src[pos] = ei[e];
    }
}

// ---------------- aggregation: gather-sum, 32 lanes per node, float4/lane ------

__global__ __launch_bounds__(256) void csr_gather(
    const float* __restrict__ x, const int* __restrict__ row_start,
    const int* __restrict__ csr_src, float* __restrict__ agg)
{
    int node = blockIdx.x * 8 + (threadIdx.x >> 5);
    int lane = threadIdx.x & 31;
    if (node >= N_NODES) return;
    int beg = row_start[node];
    int end = row_start[node + 1];
    float4 a0 = make_float4(0.f, 0.f, 0.f, 0.f);
    float4 a1 = make_float4(0.f, 0.f, 0.f, 0.f);
    int i = beg;
    for (; i + 1 < end; i += 2) {
        int s0 = csr_src[i];
        int s1 = csr_src[i + 1];
        float4 v0 = *(const float4*)(x + (size_t)s0 * D + lane * 4);
        float4 v1 = *(const float4*)(x + (size_t)s1 * D + lane * 4);
        a0.x += v0.x; a0.y += v0.y; a0.z += v0.z; a0.w += v0.w;
        a1.x += v1.x; a1.y += v1.y; a1.z += v1.z; a1.w += v1.w;
    }
    if (i < end) {
        int s0 = csr_src[i];
        float4 v0 = *(const float4*)(x + (size_t)s0 * D + lane * 4);
        a0.x += v0.x; a0.y += v0.y; a0.z += v0.z; a0.w += v0.w;
    }
    a0.x += a1.x; a0.y += a1.y; a0.z += a1.z; a0.w += a1.w;
    *(float4*)(agg + (size_t)node * D + lane * 4) = a0;
}

// ---------------- fused GEMM: O = [agg|x] @ WT + b (opt relu) ------------------

__global__ void transpose_w(const float* __restrict__ Wrel, const float* __restrict__ Wroot,
                            float* __restrict__ WT) {
    int idx = blockIdx.x * 256 + threadIdx.x;
    if (idx >= 256 * 128) return;
    int k = idx >> 7, o = idx & 127;
    WT[idx] = (k < 128) ? Wrel[o * 128 + k] : Wroot[o * 128 + (k - 128)];
}

__global__ __launch_bounds__(256) void gemm_fused(
    const float* __restrict__ A, const float* __restrict__ X,
    const float* __restrict__ WT, const float* __restrict__ bias,
    float* __restrict__ O, int relu)
{
    __shared__ float As[BM][BK + 4];
    __shared__ float Bs[BK][D];
    int tid = threadIdx.x;
    int tx = tid & 31;
    int ty = tid >> 5;
    int row0 = blockIdx.x * BM;

    float acc[8][4];
#pragma unroll
    for (int r = 0; r < 8; ++r)
#pragma unroll
        for (int c = 0; c < 4; ++c) acc[r][c] = 0.f;

    for (int kt = 0; kt < 2 * D; kt += BK) {
#pragma unroll
        for (int i = 0; i < 4; ++i) {
            int f4 = tid + i * 256;
            int k  = f4 >> 5;
            int c4 = f4 & 31;
            *(float4*)(&Bs[k][c4 * 4]) = *(const float4*)(WT + (size_t)(kt + k) * D + c4 * 4);
        }
        const float* S = (kt < D) ? A : X;
        int kk = kt & (D - 1);
#pragma unroll
        for (int i = 0; i < 2; ++i) {
            int f4 = tid + i * 256;
            int r  = f4 >> 3;
            int c4 = f4 & 7;
            int grow = row0 + r;
            float4 v = make_float4(0.f, 0.f, 0.f, 0.f);
            if (grow < N_NODES) v = *(const float4*)(S + (size_t)grow * D + kk + c4 * 4);
            *(float4*)(&As[r][c4 * 4]) = v;
        }
        __syncthreads();
#pragma unroll
        for (int k = 0; k < BK; k += 2) {
            float4 b0 = *(const float4*)(&Bs[k][tx * 4]);
            float4 b1 = *(const float4*)(&Bs[k + 1][tx * 4]);
#pragma unroll
            for (int r = 0; r < 8; ++r) {
                float2 a = *(const float2*)(&As[ty * 8 + r][k]);
                acc[r][0] += a.x * b0.x; acc[r][1] += a.x * b0.y;
                acc[r][2] += a.x * b0.z; acc[r][3] += a.x * b0.w;
                acc[r][0] += a.y * b1.x; acc[r][1] += a.y * b1.y;
                acc[r][2] += a.y * b1.z; acc[r][3] += a.y * b1.w;
            }
        }
        __syncthreads();
    }

    float4 bv = *(const float4*)(bias + tx * 4);
#pragma unroll
    for (int r = 0; r < 8; ++r) {
        int grow = row0 + ty * 8 + r;
        if (grow >= N_NODES) continue;
        float4 v;
        v.x = acc[r][0] + bv.x; v.y = acc[r][1] + bv.y;
        v.z = acc[r][2] + bv.z; v.w = acc[r][3] + bv.w;
        if (relu) {
            v.x = fmaxf(v.x, 0.f); v.y = fmaxf(v.y, 0.f);
            v.z = fmaxf(v.z, 0.f); v.w = fmaxf(v.w, 0.f);
        }
        *(float4*)(O + (size_t)grow * D + tx * 4) = v;
    }
}

// ---------------- pooling + head ----------------------------------------------

__device__ inline void atomicMaxF(float* addr, float v) {
    // int-max for non-negative, unsigned-min for negative; init must be -FLT_MAX
    if (v >= 0.f) atomicMax((int*)addr, __float_as_int(v));
    else          atomicMin((unsigned int*)addr, __float_as_uint(v));
}

// batch is sorted; block = SEG_CHUNK(32) nodes x 128 features, thread d keeps a
// running max, flushing with an atomic only at graph boundaries / chunk end.
// 1563 blocks x 2 waves => ~12 waves/CU (vs 98 blocks before: latency-bound).
__global__ __launch_bounds__(128) void seg_max(const float* __restrict__ h,
                                               const int* __restrict__ batch,
                                               float* __restrict__ g) {
    int d  = threadIdx.x;              // 128
    int n0 = blockIdx.x * SEG_CHUNK;
    int nend = min(n0 + SEG_CHUNK, N_NODES);
    int cur_b = batch[n0];
    float cur = -FLT_MAX;
    for (int n = n0; n < nend; ++n) {
        int b = batch[n];
        if (b != cur_b) {
            atomicMaxF(&g[cur_b * D + d], cur);
            cur_b = b;
            cur = -FLT_MAX;
        }
        cur = fmaxf(cur, h[(size_t)n * D + d]);
    }
    atomicMaxF(&g[cur_b * D + d], cur);
}

__global__ void mlp_head(const float* __restrict__ g,
                         const float* __restrict__ W1, const float* __restrict__ b1,
                         const float* __restrict__ W2, const float* __restrict__ b2,
                         float* __restrict__ out) {
    int gi = threadIdx.x;
    if (gi >= N_GRAPHS) return;
    float h[5];
#pragma unroll
    for (int j = 0; j < 5; ++j) {
        float acc = b1[j];
        for (int k = 0; k < D; ++k) acc += g[gi * D + k] * W1[j * D + k];
        h[j] = fmaxf(acc, 0.f);
    }
    float o = b2[0];
#pragma unroll
    for (int j = 0; j < 5; ++j) o += h[j] * W2[j];
    out[gi] = o;
}

extern "C" void kernel_launch(void* const* d_in, const int* in_sizes, int n_in,
                              void* d_out, int out_size, void* d_ws, size_t ws_size,
                              hipStream_t stream) {
    const float* x     = (const float*)d_in[0];
    const int*   ei    = (const int*)d_in[1];
    const int*   batch = (const int*)d_in[2];
    const float* Wrel[3]  = {(const float*)d_in[3], (const float*)d_in[6], (const float*)d_in[9]};
    const float* brel[3]  = {(const float*)d_in[4], (const float*)d_in[7], (const float*)d_in[10]};
    const float* Wroot[3] = {(const float*)d_in[5], (const float*)d_in[8], (const float*)d_in[11]};
    const float* W1 = (const float*)d_in[12];
    const float* b1 = (const float*)d_in[13];
    const float* W2 = (const float*)d_in[14];
    const float* b2 = (const float*)d_in[15];
    float* out = (float*)d_out;

    char* ws = (char*)d_ws;
    const size_t nodeBytes = (size_t)N_NODES * D * sizeof(float);   // 25.6 MB
    float* agg  = (float*)(ws);
    float* buf1 = (float*)(ws + nodeBytes);
    float* buf2 = (float*)(ws + 2 * nodeBytes);
    char*  p    = ws + 3 * nodeBytes;
    float* WT0  = (float*)p;            p += 256 * 128 * sizeof(float);
    float* WT1  = (float*)p;            p += 256 * 128 * sizeof(float);
    float* WT2  = (float*)p;            p += 256 * 128 * sizeof(float);
    float* g    = (float*)p;            p += N_GRAPHS * D * sizeof(float);
    int*   deg       = (int*)p;         p += N_NODES * sizeof(int);
    int*   row_start = (int*)p;         p += (N_NODES + 1) * sizeof(int);
    int*   cursor    = (int*)p;         p += N_NODES * sizeof(int);
    int*   csr_src   = (int*)p;         p += N_EDGES * sizeof(int);
    float* WT[3] = {WT0, WT1, WT2};

    // CSR build (once)
    zero_i<<<(N_NODES + 255) / 256, 256, 0, stream>>>(deg, N_NODES);
    count_deg<<<(N_EDGES + 255) / 256, 256, 0, stream>>>(ei, deg);
    scan_deg<<<1, SCAN_T, 0, stream>>>(deg, row_start, cursor);
    fill_csr<<<(N_EDGES + 255) / 256, 256, 0, stream>>>(ei, cursor, csr_src);

    for (int l = 0; l < 3; ++l)
        transpose_w<<<128, 256, 0, stream>>>(Wrel[l], Wroot[l], WT[l]);

    const float* cur = x;
    float* outs[3] = {buf1, buf2, buf1};
    for (int l = 0; l < 3; ++l) {
        csr_gather<<<(N_NODES + 7) / 8, 256, 0, stream>>>(cur, row_start, csr_src, agg);
        gemm_fused<<<(N_NODES + BM - 1) / BM, 256, 0, stream>>>(
            agg, cur, WT[l], brel[l], outs[l], (l < 2) ? 1 : 0);
        cur = outs[l];
    }

    init_neg<<<(N_GRAPHS * D + 255) / 256, 256, 0, stream>>>(g, N_GRAPHS * D);
    seg_max<<<(N_NODES + SEG_CHUNK - 1) / SEG_CHUNK, 128, 0, stream>>>(cur, batch, g);
    mlp_head<<<1, 64, 0, stream>>>(g, W1, b1, W2, b2, out);
}

// Round 4
// 478.969 us; speedup vs baseline: 7.2364x; 1.2473x over previous
//
#include <hip/hip_runtime.h>
#include <float.h>

#define N_NODES 50000
#define N_EDGES 600000
#define D 128
#define N_GRAPHS 64
#define BM 64
#define BK 32
#define SEG_CHUNK 32
#define SCAN_T 256
#define SCAN_NBLK ((N_NODES + SCAN_T - 1) / SCAN_T)   // 196

__global__ void zero_i(int* __restrict__ p, int n) {
    int i = blockIdx.x * 256 + threadIdx.x;
    if (i < n) p[i] = 0;
}

__global__ void init_neg(float* __restrict__ p, int n) {
    int i = blockIdx.x * 256 + threadIdx.x;
    if (i < n) p[i] = -FLT_MAX;
}

// ---------------- CSR build (once per launch; edge_index is layer-invariant) ----

__global__ void count_deg(const int* __restrict__ ei, int* __restrict__ deg) {
    int e = blockIdx.x * 256 + threadIdx.x;
    if (e < N_EDGES) atomicAdd(&deg[ei[N_EDGES + e]], 1);
}

// Phase 1: per-block sums of deg (196 blocks x 256)
__global__ __launch_bounds__(SCAN_T) void block_sum(const int* __restrict__ deg,
                                                    int* __restrict__ blockSums) {
    __shared__ int s[SCAN_T];
    int tid = threadIdx.x;
    int i = blockIdx.x * SCAN_T + tid;
    s[tid] = (i < N_NODES) ? deg[i] : 0;
    __syncthreads();
    for (int off = SCAN_T / 2; off > 0; off >>= 1) {
        if (tid < off) s[tid] += s[tid + off];
        __syncthreads();
    }
    if (tid == 0) blockSums[blockIdx.x] = s[0];
}

// Phase 2: single-block scan of the 196 block sums -> exclusive blockOff + total
__global__ __launch_bounds__(SCAN_T) void scan_blocks(const int* __restrict__ blockSums,
                                                      int* __restrict__ blockOff,
                                                      int* __restrict__ row_start) {
    __shared__ int s[SCAN_T];
    int tid = threadIdx.x;
    int v = (tid < SCAN_NBLK) ? blockSums[tid] : 0;
    s[tid] = v;
    __syncthreads();
    for (int off = 1; off < SCAN_T; off <<= 1) {
        int t = (tid >= off) ? s[tid - off] : 0;
        __syncthreads();
        s[tid] += t;
        __syncthreads();
    }
    if (tid < SCAN_NBLK) blockOff[tid] = s[tid] - v;          // exclusive
    if (tid == SCAN_T - 1) row_start[N_NODES] = s[tid];       // total = N_EDGES
}

// Phase 3: block-local exclusive scan + block offset -> row_start, cursor
__global__ __launch_bounds__(SCAN_T) void scan_write(const int* __restrict__ deg,
                                                     const int* __restrict__ blockOff,
                                                     int* __restrict__ row_start,
                                                     int* __restrict__ cursor) {
    __shared__ int s[SCAN_T];
    int tid = threadIdx.x;
    int i = blockIdx.x * SCAN_T + tid;
    int v = (i < N_NODES) ? deg[i] : 0;
    s[tid] = v;
    __syncthreads();
    for (int off = 1; off < SCAN_T; off <<= 1) {
        int t = (tid >= off) ? s[tid - off] : 0;
        __syncthreads();
        s[tid] += t;
        __syncthreads();
    }
    if (i < N_NODES) {
        int rs = blockOff[blockIdx.x] + s[tid] - v;           // exclusive
        row_start[i] = rs;
        cursor[i]    = rs;
    }
}

__global__ void fill_csr(const int* __restrict__ ei, int* __restrict__ cursor,
                         int* __restrict__ csr_src) {
    int e = blockIdx.x * 256 + threadIdx.x;
    if (e < N_EDGES) {
        int dst = ei[N_EDGES + e];
        int pos = atomicAdd(&cursor[dst], 1);
        csr_src[pos] = ei[e];
    }
}

// ---------------- aggregation: gather-sum, 32 lanes per node, float4/lane ------

__global__ __launch_bounds__(256) void csr_gather(
    const float* __restrict__ x, const int* __restrict__ row_start,
    const int* __restrict__ csr_src, float* __restrict__ agg)
{
    int node = blockIdx.x * 8 + (threadIdx.x >> 5);
    int lane = threadIdx.x & 31;
    if (node >= N_NODES) return;
    int beg = row_start[node];
    int end = row_start[node + 1];
    float4 a0 = make_float4(0.f, 0.f, 0.f, 0.f);
    float4 a1 = make_float4(0.f, 0.f, 0.f, 0.f);
    int i = beg;
    for (; i + 1 < end; i += 2) {
        int s0 = csr_src[i];
        int s1 = csr_src[i + 1];
        float4 v0 = *(const float4*)(x + (size_t)s0 * D + lane * 4);
        float4 v1 = *(const float4*)(x + (size_t)s1 * D + lane * 4);
        a0.x += v0.x; a0.y += v0.y; a0.z += v0.z; a0.w += v0.w;
        a1.x += v1.x; a1.y += v1.y; a1.z += v1.z; a1.w += v1.w;
    }
    if (i < end) {
        int s0 = csr_src[i];
        float4 v0 = *(const float4*)(x + (size_t)s0 * D + lane * 4);
        a0.x += v0.x; a0.y += v0.y; a0.z += v0.z; a0.w += v0.w;
    }
    a0.x += a1.x; a0.y += a1.y; a0.z += a1.z; a0.w += a1.w;
    *(float4*)(agg + (size_t)node * D + lane * 4) = a0;
}

// ---------------- fused GEMM: O = [agg|x] @ WT + b (opt relu) ------------------

__global__ void transpose_w(const float* __restrict__ Wrel, const float* __restrict__ Wroot,
                            float* __restrict__ WT) {
    int idx = blockIdx.x * 256 + threadIdx.x;
    if (idx >= 256 * 128) return;
    int k = idx >> 7, o = idx & 127;
    WT[idx] = (k < 128) ? Wrel[o * 128 + k] : Wroot[o * 128 + (k - 128)];
}

__global__ __launch_bounds__(256) void gemm_fused(
    const float* __restrict__ A, const float* __restrict__ X,
    const float* __restrict__ WT, const float* __restrict__ bias,
    float* __restrict__ O, int relu)
{
    __shared__ float As[BM][BK + 4];
    __shared__ float Bs[BK][D];
    int tid = threadIdx.x;
    int tx = tid & 31;
    int ty = tid >> 5;
    int row0 = blockIdx.x * BM;

    float acc[8][4];
#pragma unroll
    for (int r = 0; r < 8; ++r)
#pragma unroll
        for (int c = 0; c < 4; ++c) acc[r][c] = 0.f;

    for (int kt = 0; kt < 2 * D; kt += BK) {
#pragma unroll
        for (int i = 0; i < 4; ++i) {
            int f4 = tid + i * 256;
            int k  = f4 >> 5;
            int c4 = f4 & 31;
            *(float4*)(&Bs[k][c4 * 4]) = *(const float4*)(WT + (size_t)(kt + k) * D + c4 * 4);
        }
        const float* S = (kt < D) ? A : X;
        int kk = kt & (D - 1);
#pragma unroll
        for (int i = 0; i < 2; ++i) {
            int f4 = tid + i * 256;
            int r  = f4 >> 3;
            int c4 = f4 & 7;
            int grow = row0 + r;
            float4 v = make_float4(0.f, 0.f, 0.f, 0.f);
            if (grow < N_NODES) v = *(const float4*)(S + (size_t)grow * D + kk + c4 * 4);
            *(float4*)(&As[r][c4 * 4]) = v;
        }
        __syncthreads();
#pragma unroll
        for (int k = 0; k < BK; k += 2) {
            float4 b0 = *(const float4*)(&Bs[k][tx * 4]);
            float4 b1 = *(const float4*)(&Bs[k + 1][tx * 4]);
#pragma unroll
            for (int r = 0; r < 8; ++r) {
                float2 a = *(const float2*)(&As[ty * 8 + r][k]);
                acc[r][0] += a.x * b0.x; acc[r][1] += a.x * b0.y;
                acc[r][2] += a.x * b0.z; acc[r][3] += a.x * b0.w;
                acc[r][0] += a.y * b1.x; acc[r][1] += a.y * b1.y;
                acc[r][2] += a.y * b1.z; acc[r][3] += a.y * b1.w;
            }
        }
        __syncthreads();
    }

    float4 bv = *(const float4*)(bias + tx * 4);
#pragma unroll
    for (int r = 0; r < 8; ++r) {
        int grow = row0 + ty * 8 + r;
        if (grow >= N_NODES) continue;
        float4 v;
        v.x = acc[r][0] + bv.x; v.y = acc[r][1] + bv.y;
        v.z = acc[r][2] + bv.z; v.w = acc[r][3] + bv.w;
        if (relu) {
            v.x = fmaxf(v.x, 0.f); v.y = fmaxf(v.y, 0.f);
            v.z = fmaxf(v.z, 0.f); v.w = fmaxf(v.w, 0.f);
        }
        *(float4*)(O + (size_t)grow * D + tx * 4) = v;
    }
}

// ---------------- pooling + head ----------------------------------------------

__device__ inline void atomicMaxF(float* addr, float v) {
    // int-max for non-negative, unsigned-min for negative; init must be -FLT_MAX
    if (v >= 0.f) atomicMax((int*)addr, __float_as_int(v));
    else          atomicMin((unsigned int*)addr, __float_as_uint(v));
}

// batch is sorted; block = SEG_CHUNK(32) nodes x 128 features, thread d keeps a
// running max, flushing with an atomic only at graph boundaries / chunk end.
__global__ __launch_bounds__(128) void seg_max(const float* __restrict__ h,
                                               const int* __restrict__ batch,
                                               float* __restrict__ g) {
    int d  = threadIdx.x;              // 128
    int n0 = blockIdx.x * SEG_CHUNK;
    int nend = min(n0 + SEG_CHUNK, N_NODES);
    int cur_b = batch[n0];
    float cur = -FLT_MAX;
    for (int n = n0; n < nend; ++n) {
        int b = batch[n];
        if (b != cur_b) {
            atomicMaxF(&g[cur_b * D + d], cur);
            cur_b = b;
            cur = -FLT_MAX;
        }
        cur = fmaxf(cur, h[(size_t)n * D + d]);
    }
    atomicMaxF(&g[cur_b * D + d], cur);
}

__global__ void mlp_head(const float* __restrict__ g,
                         const float* __restrict__ W1, const float* __restrict__ b1,
                         const float* __restrict__ W2, const float* __restrict__ b2,
                         float* __restrict__ out) {
    int gi = threadIdx.x;
    if (gi >= N_GRAPHS) return;
    float h[5];
#pragma unroll
    for (int j = 0; j < 5; ++j) {
        float acc = b1[j];
        for (int k = 0; k < D; ++k) acc += g[gi * D + k] * W1[j * D + k];
        h[j] = fmaxf(acc, 0.f);
    }
    float o = b2[0];
#pragma unroll
    for (int j = 0; j < 5; ++j) o += h[j] * W2[j];
    out[gi] = o;
}

extern "C" void kernel_launch(void* const* d_in, const int* in_sizes, int n_in,
                              void* d_out, int out_size, void* d_ws, size_t ws_size,
                              hipStream_t stream) {
    const float* x     = (const float*)d_in[0];
    const int*   ei    = (const int*)d_in[1];
    const int*   batch = (const int*)d_in[2];
    const float* Wrel[3]  = {(const float*)d_in[3], (const float*)d_in[6], (const float*)d_in[9]};
    const float* brel[3]  = {(const float*)d_in[4], (const float*)d_in[7], (const float*)d_in[10]};
    const float* Wroot[3] = {(const float*)d_in[5], (const float*)d_in[8], (const float*)d_in[11]};
    const float* W1 = (const float*)d_in[12];
    const float* b1 = (const float*)d_in[13];
    const float* W2 = (const float*)d_in[14];
    const float* b2 = (const float*)d_in[15];
    float* out = (float*)d_out;

    char* ws = (char*)d_ws;
    const size_t nodeBytes = (size_t)N_NODES * D * sizeof(float);   // 25.6 MB
    float* agg  = (float*)(ws);
    float* buf1 = (float*)(ws + nodeBytes);
    float* buf2 = (float*)(ws + 2 * nodeBytes);
    char*  p    = ws + 3 * nodeBytes;
    float* WT0  = (float*)p;            p += 256 * 128 * sizeof(float);
    float* WT1  = (float*)p;            p += 256 * 128 * sizeof(float);
    float* WT2  = (float*)p;            p += 256 * 128 * sizeof(float);
    float* g    = (float*)p;            p += N_GRAPHS * D * sizeof(float);
    int*   deg       = (int*)p;         p += N_NODES * sizeof(int);
    int*   row_start = (int*)p;         p += (N_NODES + 1) * sizeof(int);
    int*   cursor    = (int*)p;         p += N_NODES * sizeof(int);
    int*   csr_src   = (int*)p;         p += N_EDGES * sizeof(int);
    int*   blockSums = (int*)p;         p += SCAN_NBLK * sizeof(int);
    int*   blockOff  = (int*)p;         p += SCAN_NBLK * sizeof(int);
    float* WT[3] = {WT0, WT1, WT2};

    // CSR build (once)
    zero_i<<<(N_NODES + 255) / 256, 256, 0, stream>>>(deg, N_NODES);
    count_deg<<<(N_EDGES + 255) / 256, 256, 0, stream>>>(ei, deg);
    block_sum<<<SCAN_NBLK, SCAN_T, 0, stream>>>(deg, blockSums);
    scan_blocks<<<1, SCAN_T, 0, stream>>>(blockSums, blockOff, row_start);
    scan_write<<<SCAN_NBLK, SCAN_T, 0, stream>>>(deg, blockOff, row_start, cursor);
    fill_csr<<<(N_EDGES + 255) / 256, 256, 0, stream>>>(ei, cursor, csr_src);

    for (int l = 0; l < 3; ++l)
        transpose_w<<<128, 256, 0, stream>>>(Wrel[l], Wroot[l], WT[l]);

    const float* cur = x;
    float* outs[3] = {buf1, buf2, buf1};
    for (int l = 0; l < 3; ++l) {
        csr_gather<<<(N_NODES + 7) / 8, 256, 0, stream>>>(cur, row_start, csr_src, agg);
        gemm_fused<<<(N_NODES + BM - 1) / BM, 256, 0, stream>>>(
            agg, cur, WT[l], brel[l], outs[l], (l < 2) ? 1 : 0);
        cur = outs[l];
    }

    init_neg<<<(N_GRAPHS * D + 255) / 256, 256, 0, stream>>>(g, N_GRAPHS * D);
    seg_max<<<(N_NODES + SEG_CHUNK - 1) / SEG_CHUNK, 128, 0, stream>>>(cur, batch, g);
    mlp_head<<<1, 64, 0, stream>>>(g, W1, b1, W2, b2, out);
}

// Round 5
// 407.908 us; speedup vs baseline: 8.4971x; 1.1742x over previous
//
#include <hip/hip_runtime.h>
#include <float.h>

#define N_NODES 50000
#define N_EDGES 600000
#define D 128
#define N_GRAPHS 64
#define SEG_CHUNK 32
#define SCAN_T 256
#define SCAN_NBLK ((N_NODES + SCAN_T - 1) / SCAN_T)   // 196

typedef __attribute__((ext_vector_type(8))) short short8;   // 8 bf16 = 4 VGPRs
typedef __attribute__((ext_vector_type(4))) float floatx4;

__device__ inline float bf2f(unsigned short h) {
    return __uint_as_float((unsigned)h << 16);
}
__device__ inline unsigned short f2bf(float f) {
    unsigned u = __float_as_uint(f);
    return (unsigned short)((u + 0x7fffu + ((u >> 16) & 1u)) >> 16);   // RNE
}

__global__ void zero_i(int* __restrict__ p, int n) {
    int i = blockIdx.x * 256 + threadIdx.x;
    if (i < n) p[i] = 0;
}

__global__ void init_neg(float* __restrict__ p, int n) {
    int i = blockIdx.x * 256 + threadIdx.x;
    if (i < n) p[i] = -FLT_MAX;
}

// cast fp32 x -> bf16 (vectorized float4 -> ushort4)
__global__ void cast_bf16(const float4* __restrict__ src, ushort4* __restrict__ dst, int n4) {
    int i = blockIdx.x * 256 + threadIdx.x;
    if (i >= n4) return;
    float4 v = src[i];
    ushort4 o;
    o.x = f2bf(v.x); o.y = f2bf(v.y); o.z = f2bf(v.z); o.w = f2bf(v.w);
    dst[i] = o;
}

// Bb[o][k] (bf16, 128x256): k<128 -> Wrel[o][k], else Wroot[o][k-128].
// This row-major-in-k layout IS the MFMA B-fragment layout (n fixed, k contiguous).
__global__ void conv_w(const float* __restrict__ Wrel, const float* __restrict__ Wroot,
                       unsigned short* __restrict__ Bb) {
    int idx = blockIdx.x * 256 + threadIdx.x;
    if (idx >= 128 * 256) return;
    int o = idx >> 8, k = idx & 255;
    float v = (k < 128) ? Wrel[o * 128 + k] : Wroot[o * 128 + (k - 128)];
    Bb[idx] = f2bf(v);
}

// ---------------- CSR build (once per launch) ----------------------------------

__global__ void count_deg(const int* __restrict__ ei, int* __restrict__ deg) {
    int e = blockIdx.x * 256 + threadIdx.x;
    if (e < N_EDGES) atomicAdd(&deg[ei[N_EDGES + e]], 1);
}

__global__ __launch_bounds__(SCAN_T) void block_sum(const int* __restrict__ deg,
                                                    int* __restrict__ blockSums) {
    __shared__ int s[SCAN_T];
    int tid = threadIdx.x;
    int i = blockIdx.x * SCAN_T + tid;
    s[tid] = (i < N_NODES) ? deg[i] : 0;
    __syncthreads();
    for (int off = SCAN_T / 2; off > 0; off >>= 1) {
        if (tid < off) s[tid] += s[tid + off];
        __syncthreads();
    }
    if (tid == 0) blockSums[blockIdx.x] = s[0];
}

__global__ __launch_bounds__(SCAN_T) void scan_blocks(const int* __restrict__ blockSums,
                                                      int* __restrict__ blockOff,
                                                      int* __restrict__ row_start) {
    __shared__ int s[SCAN_T];
    int tid = threadIdx.x;
    int v = (tid < SCAN_NBLK) ? blockSums[tid] : 0;
    s[tid] = v;
    __syncthreads();
    for (int off = 1; off < SCAN_T; off <<= 1) {
        int t = (tid >= off) ? s[tid - off] : 0;
        __syncthreads();
        s[tid] += t;
        __syncthreads();
    }
    if (tid < SCAN_NBLK) blockOff[tid] = s[tid] - v;
    if (tid == SCAN_T - 1) row_start[N_NODES] = s[tid];
}

__global__ __launch_bounds__(SCAN_T) void scan_write(const int* __restrict__ deg,
                                                     const int* __restrict__ blockOff,
                                                     int* __restrict__ row_start,
                                                     int* __restrict__ cursor) {
    __shared__ int s[SCAN_T];
    int tid = threadIdx.x;
    int i = blockIdx.x * SCAN_T + tid;
    int v = (i < N_NODES) ? deg[i] : 0;
    s[tid] = v;
    __syncthreads();
    for (int off = 1; off < SCAN_T; off <<= 1) {
        int t = (tid >= off) ? s[tid - off] : 0;
        __syncthreads();
        s[tid] += t;
        __syncthreads();
    }
    if (i < N_NODES) {
        int rs = blockOff[blockIdx.x] + s[tid] - v;
        row_start[i] = rs;
        cursor[i]    = rs;
    }
}

__global__ void fill_csr(const int* __restrict__ ei, int* __restrict__ cursor,
                         int* __restrict__ csr_src) {
    int e = blockIdx.x * 256 + threadIdx.x;
    if (e < N_EDGES) {
        int dst = ei[N_EDGES + e];
        int pos = atomicAdd(&cursor[dst], 1);
        csr_src[pos] = ei[e];
    }
}

// ---------------- aggregation: bf16 gather-sum, fp32 accumulate ----------------
// 32 lanes per node, 4 features/lane (8 B ushort4 loads)

__global__ __launch_bounds__(256) void csr_gather_bf16(
    const unsigned short* __restrict__ xb, const int* __restrict__ row_start,
    const int* __restrict__ csr_src, unsigned short* __restrict__ aggb)
{
    int node = blockIdx.x * 8 + (threadIdx.x >> 5);
    int lane = threadIdx.x & 31;
    if (node >= N_NODES) return;
    int beg = row_start[node];
    int end = row_start[node + 1];
    float a0x = 0.f, a0y = 0.f, a0z = 0.f, a0w = 0.f;
    float a1x = 0.f, a1y = 0.f, a1z = 0.f, a1w = 0.f;
    int i = beg;
    for (; i + 1 < end; i += 2) {
        int s0 = csr_src[i];
        int s1 = csr_src[i + 1];
        ushort4 u0 = *(const ushort4*)(xb + (size_t)s0 * D + lane * 4);
        ushort4 u1 = *(const ushort4*)(xb + (size_t)s1 * D + lane * 4);
        a0x += bf2f(u0.x); a0y += bf2f(u0.y); a0z += bf2f(u0.z); a0w += bf2f(u0.w);
        a1x += bf2f(u1.x); a1y += bf2f(u1.y); a1z += bf2f(u1.z); a1w += bf2f(u1.w);
    }
    if (i < end) {
        int s0 = csr_src[i];
        ushort4 u0 = *(const ushort4*)(xb + (size_t)s0 * D + lane * 4);
        a0x += bf2f(u0.x); a0y += bf2f(u0.y); a0z += bf2f(u0.z); a0w += bf2f(u0.w);
    }
    ushort4 r;
    r.x = f2bf(a0x + a1x); r.y = f2bf(a0y + a1y);
    r.z = f2bf(a0z + a1z); r.w = f2bf(a0w + a1w);
    *(ushort4*)(aggb + (size_t)node * D + lane * 4) = r;
}

// ---------------- MFMA GEMM: O = [aggb|xb] @ Bb^T + bias (opt relu) ------------
// block = 4 waves x 16 rows = 64 rows; 8 n-tiles x 8 k-steps of 16x16x32 bf16.
// No LDS: a_frag/b_frag are 16B k-contiguous global loads; Bb (64 KB) is L1/L2-hot.

__global__ __launch_bounds__(256) void gemm_mfma(
    const unsigned short* __restrict__ aggb, const unsigned short* __restrict__ xb,
    const unsigned short* __restrict__ Bb, const float* __restrict__ bias,
    unsigned short* __restrict__ Ob, int relu)
{
    int tid  = threadIdx.x;
    int wave = tid >> 6;
    int lane = tid & 63;
    int m    = lane & 15;          // row within 16-row tile / out-col within n-tile
    int quad = lane >> 4;          // 0..3
    int row0 = blockIdx.x * 64 + wave * 16;

    floatx4 acc[8];
#pragma unroll
    for (int t = 0; t < 8; ++t) acc[t] = (floatx4){0.f, 0.f, 0.f, 0.f};

    int arow = row0 + m;
    if (arow > N_NODES - 1) arow = N_NODES - 1;   // clamp; stores guarded below

#pragma unroll
    for (int ks = 0; ks < 8; ++ks) {
        int k0 = ks * 32;
        const unsigned short* Asrc = (k0 < 128) ? aggb : xb;
        int kk = k0 & 127;
        short8 a = *(const short8*)(Asrc + (size_t)arow * 128 + kk + quad * 8);
#pragma unroll
        for (int t = 0; t < 8; ++t) {
            short8 b = *(const short8*)(Bb + (size_t)(t * 16 + m) * 256 + k0 + quad * 8);
            acc[t] = __builtin_amdgcn_mfma_f32_16x16x32_bf16(a, b, acc[t], 0, 0, 0);
        }
    }

#pragma unroll
    for (int t = 0; t < 8; ++t) {
        int col = t * 16 + m;                     // C/D: col=lane&15
        float bv = bias[col];
#pragma unroll
        for (int r = 0; r < 4; ++r) {
            int row = row0 + quad * 4 + r;        // C/D: row=quad*4+reg
            if (row >= N_NODES) continue;
            float v = acc[t][r] + bv;
            if (relu) v = fmaxf(v, 0.f);
            Ob[(size_t)row * D + col] = f2bf(v);
        }
    }
}

// ---------------- pooling + head ----------------------------------------------

__device__ inline void atomicMaxF(float* addr, float v) {
    if (v >= 0.f) atomicMax((int*)addr, __float_as_int(v));
    else          atomicMin((unsigned int*)addr, __float_as_uint(v));
}

__global__ __launch_bounds__(128) void seg_max(const unsigned short* __restrict__ h,
                                               const int* __restrict__ batch,
                                               float* __restrict__ g) {
    int d  = threadIdx.x;
    int n0 = blockIdx.x * SEG_CHUNK;
    int nend = min(n0 + SEG_CHUNK, N_NODES);
    int cur_b = batch[n0];
    float cur = -FLT_MAX;
    for (int n = n0; n < nend; ++n) {
        int b = batch[n];
        if (b != cur_b) {
            atomicMaxF(&g[cur_b * D + d], cur);
            cur_b = b;
            cur = -FLT_MAX;
        }
        cur = fmaxf(cur, bf2f(h[(size_t)n * D + d]));
    }
    atomicMaxF(&g[cur_b * D + d], cur);
}

__global__ void mlp_head(const float* __restrict__ g,
                         const float* __restrict__ W1, const float* __restrict__ b1,
                         const float* __restrict__ W2, const float* __restrict__ b2,
                         float* __restrict__ out) {
    int gi = threadIdx.x;
    if (gi >= N_GRAPHS) return;
    float h[5];
#pragma unroll
    for (int j = 0; j < 5; ++j) {
        float acc = b1[j];
        for (int k = 0; k < D; ++k) acc += g[gi * D + k] * W1[j * D + k];
        h[j] = fmaxf(acc, 0.f);
    }
    float o = b2[0];
#pragma unroll
    for (int j = 0; j < 5; ++j) o += h[j] * W2[j];
    out[gi] = o;
}

extern "C" void kernel_launch(void* const* d_in, const int* in_sizes, int n_in,
                              void* d_out, int out_size, void* d_ws, size_t ws_size,
                              hipStream_t stream) {
    const float* x     = (const float*)d_in[0];
    const int*   ei    = (const int*)d_in[1];
    const int*   batch = (const int*)d_in[2];
    const float* Wrel[3]  = {(const float*)d_in[3], (const float*)d_in[6], (const float*)d_in[9]};
    const float* brel[3]  = {(const float*)d_in[4], (const float*)d_in[7], (const float*)d_in[10]};
    const float* Wroot[3] = {(const float*)d_in[5], (const float*)d_in[8], (const float*)d_in[11]};
    const float* W1 = (const float*)d_in[12];
    const float* b1 = (const float*)d_in[13];
    const float* W2 = (const float*)d_in[14];
    const float* b2 = (const float*)d_in[15];
    float* out = (float*)d_out;

    char* ws = (char*)d_ws;
    const size_t nodeB16 = (size_t)N_NODES * D * sizeof(unsigned short);   // 12.8 MB
    unsigned short* xb   = (unsigned short*)(ws);
    unsigned short* aggb = (unsigned short*)(ws + nodeB16);
    unsigned short* hb1  = (unsigned short*)(ws + 2 * nodeB16);
    unsigned short* hb2  = (unsigned short*)(ws + 3 * nodeB16);
    char* p = ws + 4 * nodeB16;
    unsigned short* Bb0 = (unsigned short*)p;   p += 128 * 256 * sizeof(unsigned short);
    unsigned short* Bb1 = (unsigned short*)p;   p += 128 * 256 * sizeof(unsigned short);
    unsigned short* Bb2 = (unsigned short*)p;   p += 128 * 256 * sizeof(unsigned short);
    float* g        = (float*)p;                p += N_GRAPHS * D * sizeof(float);
    int*   deg      = (int*)p;                  p += N_NODES * sizeof(int);
    int*   row_start= (int*)p;                  p += (N_NODES + 1) * sizeof(int);
    int*   cursor   = (int*)p;                  p += N_NODES * sizeof(int);
    int*   csr_src  = (int*)p;                  p += N_EDGES * sizeof(int);
    int*   blockSums= (int*)p;                  p += SCAN_NBLK * sizeof(int);
    int*   blockOff = (int*)p;                  p += SCAN_NBLK * sizeof(int);
    unsigned short* Bb[3] = {Bb0, Bb1, Bb2};

    // CSR build (once)
    zero_i<<<(N_NODES + 255) / 256, 256, 0, stream>>>(deg, N_NODES);
    count_deg<<<(N_EDGES + 255) / 256, 256, 0, stream>>>(ei, deg);
    block_sum<<<SCAN_NBLK, SCAN_T, 0, stream>>>(deg, blockSums);
    scan_blocks<<<1, SCAN_T, 0, stream>>>(blockSums, blockOff, row_start);
    scan_write<<<SCAN_NBLK, SCAN_T, 0, stream>>>(deg, blockOff, row_start, cursor);
    fill_csr<<<(N_EDGES + 255) / 256, 256, 0, stream>>>(ei, cursor, csr_src);

    // bf16 conversions
    const int n4 = N_NODES * D / 4;
    cast_bf16<<<(n4 + 255) / 256, 256, 0, stream>>>((const float4*)x, (ushort4*)xb, n4);
    for (int l = 0; l < 3; ++l)
        conv_w<<<128, 256, 0, stream>>>(Wrel[l], Wroot[l], Bb[l]);

    const unsigned short* cur = xb;
    unsigned short* outs[3] = {hb1, hb2, hb1};
    const int gemm_grid = (N_NODES + 63) / 64;   // 782
    for (int l = 0; l < 3; ++l) {
        csr_gather_bf16<<<(N_NODES + 7) / 8, 256, 0, stream>>>(cur, row_start, csr_src, aggb);
        gemm_mfma<<<gemm_grid, 256, 0, stream>>>(aggb, cur, Bb[l], brel[l], outs[l], (l < 2) ? 1 : 0);
        cur = outs[l];
    }

    init_neg<<<(N_GRAPHS * D + 255) / 256, 256, 0, stream>>>(g, N_GRAPHS * D);
    seg_max<<<(N_NODES + SEG_CHUNK - 1) / SEG_CHUNK, 128, 0, stream>>>(cur, batch, g);
    mlp_head<<<1, 64, 0, stream>>>(g, W1, b1, W2, b2, out);
}